// Round 15
// baseline (949.411 us; speedup 1.0000x reference)
//
#include <hip/hip_runtime.h>
#include <hip/hip_bf16.h>

// ELMo 2-layer biLSTM, B=64 T=256 U=256. Persistent RNN, data-tagged sync.
//  R15 = R14 (618us) with HALVED SYNC PARTICIPANTS: 8 WGs/cluster x 32 units
//  (grid 64) instead of 16 x 16. Cluster h-tile, ring layout, tag protocol,
//  poll window (64B/thread), stage swizzle, barrier skeleton: R14-identical.
//  Local deltas only: wreg[32] (2 N-tiles/wave), zpart 32KB, combine = 2
//  cells/thread (2 ring + 2 deferred-out stores -> poll iter1 VMCNT(2)).
//  Convoy: max-of-8 (was 16); chip poll demand halved.
//  LEDGER RULES: full-window poll ONLY (R7/R8/R13 hang); agent scope sc0 sc1
//  only (R12 livelock); ring stores must stay coalesced (R11 regression).

#define TT 256
#define TM 255
#define NU 256
#define NG 1024
#define BB 64

typedef __attribute__((ext_vector_type(8))) short short8;
typedef __attribute__((ext_vector_type(4))) float f32x4;
typedef __attribute__((ext_vector_type(4))) unsigned int u32x4;

__device__ __forceinline__ unsigned short f2bf(float v) {
  unsigned int x = __float_as_uint(v);
  return (unsigned short)((x + 0x7FFFu + ((x >> 16) & 1u)) >> 16);
}
__device__ __forceinline__ float sigm(float x) { return 1.f / (1.f + __expf(-x)); }
__device__ __forceinline__ float tanhp(float x) {
  x = fminf(fmaxf(x, -15.f), 15.f);
  float e = __expf(-2.f * x);
  return (1.f - e) / (1.f + e);
}
#define VMCNT(n) asm volatile("s_waitcnt vmcnt(" #n ")" ::: "memory")
#define LGKM0() asm volatile("s_waitcnt lgkmcnt(0)" ::: "memory")
#define SCHEDBAR() __builtin_amdgcn_sched_barrier(0)
#define BAR() __builtin_amdgcn_s_barrier()

#define LLC_LOAD16(dst, ptr) \
  asm volatile("global_load_dwordx4 %0, %1, off sc0 sc1" : "=&v"(dst) : "v"(ptr) : "memory")
#define CACH_LOAD16(dst, ptr) \
  asm volatile("global_load_dwordx4 %0, %1, off" : "=&v"(dst) : "v"(ptr) : "memory")
#define STORE4(ptr, val) \
  asm volatile("global_store_dword %0, %1, off" :: "v"(ptr), "v"(val) : "memory")

__global__ void embed_kernel(const int* __restrict__ seqs, const float* __restrict__ E,
                             unsigned short* __restrict__ embb, float* __restrict__ out) {
  int b = blockIdx.x, t = blockIdx.y, d = threadIdx.x;
  int s = seqs[b * TT + t];
  float v = E[(size_t)s * NU + d];
  embb[((size_t)(b * TT + t)) * NU + d] = f2bf(v);
  if (t < TM) out[(((size_t)(0 * BB + b)) * TM + t) * NU + d] = v;
  if (t >= 1) out[(((size_t)(3 * BB + b)) * TM + (t - 1)) * NU + d] = v;
}

__launch_bounds__(512, 1)
__global__ void lstm_kernel(const int* __restrict__ seqs,
                            const float* __restrict__ Wf, const float* __restrict__ Uf,
                            const float* __restrict__ bf,
                            const float* __restrict__ Wb, const float* __restrict__ Ub,
                            const float* __restrict__ bb,
                            const unsigned short* __restrict__ embb,
                            unsigned int* __restrict__ Hbuf, float* __restrict__ out) {
  extern __shared__ char smem[];
  float* zpart = (float*)smem;                    // [2][4][2][2][16][16] f32 = 32KB
  char* hlb0 = smem + 32768;                      // 8KB swizzled h0 tile
  char* hlb1 = smem + 40960;                      // 8KB swizzled h1 tile
  unsigned char* mskl = (unsigned char*)(smem + 49152);  // [64][256] = 16KB

  const int tid = threadIdx.x;
  const int blk = blockIdx.x;
  const int cluster = blk & 7, slice = blk >> 3;  // 8 slices; cluster->XCD (perf)
  const int dir = cluster >> 2, rg = cluster & 3;
  const int ubase = slice << 5;                   // 32 units per slice
  const int wave = tid >> 6, g = wave & 3, kh = wave >> 2;
  const int lane = tid & 63, q = lane >> 4, n15 = lane & 15;
  const int tlay = tid >> 8, ct = tid & 255, crow = ct >> 4, cn = ct & 15;
  const int brow = rg * 16 + crow;

  const float* W0 = dir ? Wb : Wf;
  const float* U0 = dir ? Ub : Uf;
  const float* b0p = dir ? bb : bf;
  const float* mats[4] = {W0, U0, W0 + NU * NG, U0 + NU * NG};

  // ---- weights -> VGPRs: wreg[(m*4+kb)*2+nt][j] =
  //      mat[kh*128+kb*32+q*8+j][g*256 + ubase + nt*16 + n15]
  short8 wreg[32];
  {
    #pragma unroll
    for (int m = 0; m < 4; m++) {
      #pragma unroll
      for (int kb = 0; kb < 4; kb++) {
        #pragma unroll
        for (int nt = 0; nt < 2; nt++) {
          const int col = g * 256 + ubase + nt * 16 + n15;
          short8 t;
          #pragma unroll
          for (int j = 0; j < 8; j++)
            t[j] = (short)f2bf(mats[m][(size_t)(kh * 128 + kb * 32 + q * 8 + j) * NG + col]);
          wreg[(m * 4 + kb) * 2 + nt] = t;
        }
      }
    }
  }

  // ---- mask table (LDS)
  for (int i = tid; i < 64 * 256; i += 512) {
    int row = i >> 8, s = i & 255;
    mskl[i] = (s < TM) ? (seqs[row * TT + (dir ? TM - s : s)] != 0) : 0;
  }

  // combine thread: 2 cells, units uA=ubase+cn, uB=ubase+cn+16
  float biA[4], biB[4];
  {
    const float* bp = tlay ? (b0p + NG) : b0p;
    #pragma unroll
    for (int gg = 0; gg < 4; gg++) {
      biA[gg] = bp[(gg << 8) + ubase + cn];
      biB[gg] = bp[(gg << 8) + ubase + cn + 16];
    }
  }
  float cstA = 0.f, hvA = 0.f, cstB = 0.f, hvB = 0.f;

  __syncthreads();

  const int wsw = (tid * 16) ^ (((tid >> 5) & 7) << 4);
  const int fb = n15 * 512 + kh * 256;
  const int fx = (n15 & 7) << 4;
  // zpart write base for (g,kh,nt): ((g*4 + kh*2 + nt)*256 + n15; L1 at +4096
  // ring word slots (2 cells): [lay][parity][cluster][4096]
  unsigned int* hstA = Hbuf + ((size_t)(tlay * 16 + cluster)) * 4096 + crow * 256 + ubase + cn;
  unsigned int* hstB = hstA + 16;
  float* dump = (float*)((char*)Hbuf + 524288) + (size_t)(blk * 512 + tid) * 2;

  const float* pendAA = dump;
  const float* pendAB = dump + 1;
  float pendVA = 0.f, pendVB = 0.f;
  bool havePend = false;

  short8 ea[4];  // emb A-frags for CURRENT tick (prefetched previous tick)

  // ================= tick 0: emb-only, L0 combine =================
  {
    int tx = dir ? TM : 0;
    const unsigned short* ep =
        embb + ((size_t)((rg * 16 + n15) * TT + tx)) * NU + kh * 128 + q * 8;
    f32x4 accN0 = {0.f, 0.f, 0.f, 0.f}, accN1 = {0.f, 0.f, 0.f, 0.f};
    #pragma unroll
    for (int kb = 0; kb < 4; kb++) {
      short8 a = *(const short8*)(ep + kb * 32);
      accN0 = __builtin_amdgcn_mfma_f32_16x16x32_bf16(a, wreg[kb * 2 + 0], accN0, 0, 0, 0);
      accN1 = __builtin_amdgcn_mfma_f32_16x16x32_bf16(a, wreg[kb * 2 + 1], accN1, 0, 0, 0);
    }
    #pragma unroll
    for (int j = 0; j < 4; j++) {
      zpart[(g * 4 + kh * 2 + 0) * 256 + (((q << 2) + j) << 4) + n15] = accN0[j];
      zpart[(g * 4 + kh * 2 + 1) * 256 + (((q << 2) + j) << 4) + n15] = accN1[j];
    }
    LGKM0(); SCHEDBAR(); BAR();
    if (tlay == 0) {
      float zA[4], zB[4];
      #pragma unroll
      for (int gg = 0; gg < 4; gg++) {
        zA[gg] = zpart[(gg * 4 + 0) * 256 + crow * 16 + cn] +
                 zpart[(gg * 4 + 2) * 256 + crow * 16 + cn] + biA[gg];
        zB[gg] = zpart[(gg * 4 + 1) * 256 + crow * 16 + cn] +
                 zpart[(gg * 4 + 3) * 256 + crow * 16 + cn] + biB[gg];
      }
      float cA = sigm(zA[1]) * cstA + sigm(zA[0]) * tanhp(zA[2]);
      float hA = sigm(zA[3]) * tanhp(cA);
      float cB = sigm(zB[1]) * cstB + sigm(zB[0]) * tanhp(zB[2]);
      float hB = sigm(zB[3]) * tanhp(cB);
      if (mskl[brow * 256 + 0]) { cstA = cA; hvA = hA; cstB = cB; hvB = hB; }
      int tout = dir ? TM - 1 : 0;
      pendAA = out + (((size_t)((1 + dir * 3) * BB + brow)) * TM + tout) * NU + ubase + cn;
      pendAB = pendAA + 16;
      pendVA = hvA; pendVB = hvB;
    }
    havePend = true;  // tlay1: dummy pends (dump) balance the ledger
    {  // emb prefetch for tick 1 (before ring stores: tick-start VMCNT(2))
      int tx1 = dir ? TM - 1 : 1;
      const unsigned short* e1 =
          embb + ((size_t)((rg * 16 + n15) * TT + tx1)) * NU + kh * 128 + q * 8;
      #pragma unroll
      for (int kb = 0; kb < 4; kb++) CACH_LOAD16(ea[kb], e1 + kb * 32);
    }
    SCHEDBAR();
    __hip_atomic_store(hstA, (1u << 16) | (unsigned)f2bf(hvA),
                       __ATOMIC_RELAXED, __HIP_MEMORY_SCOPE_AGENT);
    __hip_atomic_store(hstB, (1u << 16) | (unsigned)f2bf(hvB),
                       __ATOMIC_RELAXED, __HIP_MEMORY_SCOPE_AGENT);
  }

  // ================= ticks 1..255 =================
  for (int tau = 1; tau < 256; ++tau) {
    const bool doL0 = (tau < TM);
    const bool doH1 = (tau >= 2);
    const int step = tlay ? tau - 1 : tau;

    // tick start: drain 4 ea prefetch loads; 2 ring stores may stay pending
    VMCNT(2); SCHEDBAR();

    // pre-poll emb MFMAs (pure reg)
    f32x4 a0N0 = {0.f, 0.f, 0.f, 0.f}, a0N1 = {0.f, 0.f, 0.f, 0.f};
    f32x4 a1N0 = {0.f, 0.f, 0.f, 0.f}, a1N1 = {0.f, 0.f, 0.f, 0.f};
    if (doL0) {
      #pragma unroll
      for (int kb = 0; kb < 4; kb++) {
        a0N0 = __builtin_amdgcn_mfma_f32_16x16x32_bf16(ea[kb], wreg[kb * 2 + 0], a0N0, 0, 0, 0);
        a0N1 = __builtin_amdgcn_mfma_f32_16x16x32_bf16(ea[kb], wreg[kb * 2 + 1], a0N1, 0, 0, 0);
      }
      SCHEDBAR();
    }

    // ---- poll tagged h words (FULL window; R14 shape; pends ride iter1)
    const unsigned tg = (unsigned)tau;
    const int p = (tau + 1) & 1;
    const unsigned int* c0a = Hbuf + ((size_t)(p * 8 + cluster)) * 4096 + tid * 8;
    const unsigned int* c0b = c0a + 4;
    const unsigned int* c1a = Hbuf + ((size_t)((2 + p) * 8 + cluster)) * 4096 + tid * 8;
    const unsigned int* c1b = c1a + 4;
    u32x4 a0 = {0, 0, 0, 0}, a1 = {0, 0, 0, 0}, b0v = {0, 0, 0, 0}, b1v = {0, 0, 0, 0};
    bool first = true;
    int miss = 0;
    for (;;) {
      LLC_LOAD16(a0, c0a);
      LLC_LOAD16(a1, c0b);
      if (doH1) { LLC_LOAD16(b0v, c1a); LLC_LOAD16(b1v, c1b); }
      if (first) {
        if (havePend) { STORE4(pendAA, pendVA); STORE4(pendAB, pendVB); havePend = false; }
        first = false;
        VMCNT(2);
      } else {
        VMCNT(0);
      }
      SCHEDBAR();
      bool ok = (a0[0] >> 16) == tg && (a0[1] >> 16) == tg && (a0[2] >> 16) == tg &&
                (a0[3] >> 16) == tg && (a1[0] >> 16) == tg && (a1[1] >> 16) == tg &&
                (a1[2] >> 16) == tg && (a1[3] >> 16) == tg;
      if (doH1)
        ok = ok && (b0v[0] >> 16) == tg && (b0v[1] >> 16) == tg && (b0v[2] >> 16) == tg &&
             (b0v[3] >> 16) == tg && (b1v[0] >> 16) == tg && (b1v[1] >> 16) == tg &&
             (b1v[2] >> 16) == tg && (b1v[3] >> 16) == tg;
      if (__all(ok)) break;
      if (++miss > 2) __builtin_amdgcn_s_sleep(1);
    }
    // strip tags -> packed bf16, stage to swizzled LDS
    u32x4 s0, s1;
    s0[0] = (a0[0] & 0xFFFFu) | (a0[1] << 16);
    s0[1] = (a0[2] & 0xFFFFu) | (a0[3] << 16);
    s0[2] = (a1[0] & 0xFFFFu) | (a1[1] << 16);
    s0[3] = (a1[2] & 0xFFFFu) | (a1[3] << 16);
    *(u32x4*)(hlb0 + wsw) = s0;
    if (doH1) {
      s1[0] = (b0v[0] & 0xFFFFu) | (b0v[1] << 16);
      s1[1] = (b0v[2] & 0xFFFFu) | (b0v[3] << 16);
      s1[2] = (b1v[0] & 0xFFFFu) | (b1v[1] << 16);
      s1[3] = (b1v[2] & 0xFFFFu) | (b1v[3] << 16);
      *(u32x4*)(hlb1 + wsw) = s1;
    }
    LGKM0(); SCHEDBAR(); BAR();

    // ---- h MFMAs (A from LDS, B from wreg; h frags shared across nt)
    #pragma unroll
    for (int kb = 0; kb < 4; kb++) {
      short8 h0f = *(const short8*)(hlb0 + ((fb + kb * 64 + q * 16) ^ fx));
      if (doL0) {
        a0N0 = __builtin_amdgcn_mfma_f32_16x16x32_bf16(h0f, wreg[(4 + kb) * 2 + 0], a0N0, 0, 0, 0);
        a0N1 = __builtin_amdgcn_mfma_f32_16x16x32_bf16(h0f, wreg[(4 + kb) * 2 + 1], a0N1, 0, 0, 0);
      }
      a1N0 = __builtin_amdgcn_mfma_f32_16x16x32_bf16(h0f, wreg[(8 + kb) * 2 + 0], a1N0, 0, 0, 0);
      a1N1 = __builtin_amdgcn_mfma_f32_16x16x32_bf16(h0f, wreg[(8 + kb) * 2 + 1], a1N1, 0, 0, 0);
    }
    if (doH1) {
      #pragma unroll
      for (int kb = 0; kb < 4; kb++) {
        short8 h1f = *(const short8*)(hlb1 + ((fb + kb * 64 + q * 16) ^ fx));
        a1N0 = __builtin_amdgcn_mfma_f32_16x16x32_bf16(h1f, wreg[(12 + kb) * 2 + 0], a1N0, 0, 0, 0);
        a1N1 = __builtin_amdgcn_mfma_f32_16x16x32_bf16(h1f, wreg[(12 + kb) * 2 + 1], a1N1, 0, 0, 0);
      }
    }

    // ---- z partials ([L0|L1 at +4096]; (g,kh,nt) lanes)
    if (doL0) {
      #pragma unroll
      for (int j = 0; j < 4; j++) {
        zpart[(g * 4 + kh * 2 + 0) * 256 + (((q << 2) + j) << 4) + n15] = a0N0[j];
        zpart[(g * 4 + kh * 2 + 1) * 256 + (((q << 2) + j) << 4) + n15] = a0N1[j];
      }
    }
    #pragma unroll
    for (int j = 0; j < 4; j++) {
      zpart[4096 + (g * 4 + kh * 2 + 0) * 256 + (((q << 2) + j) << 4) + n15] = a1N0[j];
      zpart[4096 + (g * 4 + kh * 2 + 1) * 256 + (((q << 2) + j) << 4) + n15] = a1N1[j];
    }
    LGKM0(); SCHEDBAR(); BAR();

    // ---- emb prefetch for tick tau+1 (before ring stores; all threads)
    if (tau < TM - 1) {
      int tx1 = dir ? TM - (tau + 1) : (tau + 1);
      const unsigned short* e1 =
          embb + ((size_t)((rg * 16 + n15) * TT + tx1)) * NU + kh * 128 + q * 8;
      #pragma unroll
      for (int kb = 0; kb < 4; kb++) CACH_LOAD16(ea[kb], e1 + kb * 32);
    }
    SCHEDBAR();

    // ---- combine: 2 cells/thread (uA=cn, uB=cn+16)
    if (tlay ? true : doL0) {
      float zA[4], zB[4];
      #pragma unroll
      for (int gg = 0; gg < 4; gg++) {
        zA[gg] = zpart[tlay * 4096 + (gg * 4 + 0) * 256 + crow * 16 + cn] +
                 zpart[tlay * 4096 + (gg * 4 + 2) * 256 + crow * 16 + cn] + biA[gg];
        zB[gg] = zpart[tlay * 4096 + (gg * 4 + 1) * 256 + crow * 16 + cn] +
                 zpart[tlay * 4096 + (gg * 4 + 3) * 256 + crow * 16 + cn] + biB[gg];
      }
      float cA = sigm(zA[1]) * cstA + sigm(zA[0]) * tanhp(zA[2]);
      float hA = sigm(zA[3]) * tanhp(cA);
      float cB = sigm(zB[1]) * cstB + sigm(zB[0]) * tanhp(zB[2]);
      float hB = sigm(zB[3]) * tanhp(cB);
      if (mskl[brow * 256 + step]) { cstA = cA; hvA = hA; cstB = cB; hvB = hB; }
      // ring stores: tag tau+1, parity tau&1, fire-and-forget sc1
      unsigned twA = ((unsigned)(tau + 1) << 16) | (unsigned)f2bf(hvA);
      unsigned twB = ((unsigned)(tau + 1) << 16) | (unsigned)f2bf(hvB);
      __hip_atomic_store(hstA + (size_t)(tau & 1) * 32768, twA,
                         __ATOMIC_RELAXED, __HIP_MEMORY_SCOPE_AGENT);
      __hip_atomic_store(hstB + (size_t)(tau & 1) * 32768, twB,
                         __ATOMIC_RELAXED, __HIP_MEMORY_SCOPE_AGENT);
      // defer fp32 out stores to next tick's poll
      int tout = dir ? TM - 1 - step : step;
      pendAA = out + (((size_t)((1 + tlay + dir * 3) * BB + brow)) * TM + tout) * NU + ubase + cn;
      pendAB = pendAA + 16;
      pendVA = hvA; pendVB = hvB;
      havePend = true;
    }
  }

  // flush last deferred stores (tlay1's step 254)
  if (havePend) { STORE4(pendAA, pendVA); STORE4(pendAB, pendVB); }
}

extern "C" void kernel_launch(void* const* d_in, const int* in_sizes, int n_in,
                              void* d_out, int out_size, void* d_ws, size_t ws_size,
                              hipStream_t stream) {
  const int* seqs = (const int*)d_in[0];
  const float* E = (const float*)d_in[1];
  const float* Wf = (const float*)d_in[2];
  const float* Uf = (const float*)d_in[3];
  const float* bfp = (const float*)d_in[4];
  const float* Wb = (const float*)d_in[5];
  const float* Ub = (const float*)d_in[6];
  const float* bbp = (const float*)d_in[7];
  float* out = (float*)d_out;

  char* ws = (char*)d_ws;
  unsigned int* Hbuf = (unsigned int*)ws;                 // 512KB ring + 256KB dump
  unsigned short* embb = (unsigned short*)(ws + 1048576); // 8MB bf16 emb

  hipMemsetAsync(Hbuf, 0, 4 * 8 * 4096 * sizeof(unsigned int), stream);

  hipLaunchKernelGGL(embed_kernel, dim3(BB, TT), dim3(256), 0, stream,
                     seqs, E, embb, out);

  int smem = 65536;  // 32K zpart + 2x8K h tiles + 16K mask
  hipFuncSetAttribute(reinterpret_cast<const void*>(lstm_kernel),
                      hipFuncAttributeMaxDynamicSharedMemorySize, smem);
  hipLaunchKernelGGL(lstm_kernel, dim3(64), dim3(512), smem, stream,
                     seqs, Wf, Uf, bfp, Wb, Ub, bbp, embb, Hbuf, out);
}